// Round 1
// baseline (6198.047 us; speedup 1.0000x reference)
//
#include <hip/hip_runtime.h>

#define BH 64
#define KLEN 4096
#define QLEN 512
#define DIM 128
#define RP 32
#define NSWEEP 8

// ---------------- zero init for accumulation buffers ----------------
__global__ __launch_bounds__(256) void zero_kernel(float4* __restrict__ p) {
    p[(size_t)blockIdx.x * 256 + threadIdx.x] = make_float4(0.f, 0.f, 0.f, 0.f);
}

// ---------------- Gram: G = K^T K (partial over kv-chunks), S = column sums ----------------
__global__ __launch_bounds__(256) void gram_kernel(const float* __restrict__ K,
                                                   float* __restrict__ G,
                                                   float* __restrict__ S) {
    int bh = blockIdx.y, chunk = blockIdx.x;                  // 4 chunks of 1024 rows
    const float* Kb = K + ((size_t)bh * KLEN + (size_t)chunk * 1024) * DIM;
    __shared__ float Kt[32][129];                             // +1 pad: conflict-free column sums
    int t = threadIdx.x;
    int ty = t >> 4, tx = t & 15;                             // 16x16 threads, each 8x8 tile of C
    float acc[8][8];
#pragma unroll
    for (int i = 0; i < 8; i++)
#pragma unroll
        for (int j = 0; j < 8; j++) acc[i][j] = 0.f;
    float s_acc = 0.f;
    for (int tile = 0; tile < 32; tile++) {
        __syncthreads();
        for (int k = 0; k < 16; k++) {                        // load 32x128 coalesced
            int idx = t + k * 256;
            Kt[idx >> 7][idx & 127] = Kb[tile * 32 * DIM + idx];
        }
        __syncthreads();
#pragma unroll 4
        for (int r = 0; r < 32; r++) {
            float a_[8], b_[8];
#pragma unroll
            for (int i = 0; i < 8; i++) a_[i] = Kt[r][ty * 8 + i];
#pragma unroll
            for (int j = 0; j < 8; j++) b_[j] = Kt[r][tx * 8 + j];
#pragma unroll
            for (int i = 0; i < 8; i++)
#pragma unroll
                for (int j = 0; j < 8; j++) acc[i][j] += a_[i] * b_[j];
        }
        if (t < 128) { float ss = 0.f; for (int r = 0; r < 32; r++) ss += Kt[r][t]; s_acc += ss; }
    }
    float* Gb = G + (size_t)bh * DIM * DIM;
#pragma unroll
    for (int i = 0; i < 8; i++)
#pragma unroll
        for (int j = 0; j < 8; j++) atomicAdd(&Gb[(ty * 8 + i) * DIM + tx * 8 + j], acc[i][j]);
    if (t < 128) atomicAdd(&S[bh * DIM + t], s_acc);
}

// ---------------- Jacobi eigensolver on C = G - S S^T / n, top-32 basis -> Bout ----------------
__global__ __launch_bounds__(256) void jacobi_kernel(const float* __restrict__ G,
                                                     const float* __restrict__ S,
                                                     float* __restrict__ Bout) {
    __shared__ float C[128][129];   // +1 pad
    __shared__ float Vm[128][129];
    __shared__ int   pA[64], qA[64];
    __shared__ float cA[64], sA[64];
    __shared__ float diag[128];
    int bh = blockIdx.x, t = threadIdx.x;
    const float* Gb = G + (size_t)bh * DIM * DIM;
    const float* Sb = S + bh * DIM;
    for (int k = 0; k < 64; k++) {
        int idx = t + k * 256;
        int i = idx >> 7, j = idx & 127;
        C[i][j] = Gb[idx] - Sb[i] * Sb[j] * (1.0f / 4096.0f);
        Vm[i][j] = (i == j) ? 1.0f : 0.0f;
    }
    __syncthreads();
    for (int sweep = 0; sweep < NSWEEP; sweep++) {
        for (int r = 0; r < 127; r++) {
            if (t < 64) {  // angle phase: tournament pairing, Golub-Van Loan symmetric Schur
                int p, q;
                if (t == 0) { p = 127; q = r; }
                else { p = (r + t) % 127; q = (r + 127 - t) % 127; }
                float app = C[p][p], aqq = C[q][q], apq = C[p][q];
                float c = 1.0f, s = 0.0f;
                if (apq != 0.0f) {
                    float tau = (aqq - app) / (2.0f * apq);
                    float root = sqrtf(1.0f + tau * tau);
                    float tt = (tau >= 0.0f) ? 1.0f / (tau + root) : 1.0f / (tau - root);
                    c = 1.0f / sqrtf(1.0f + tt * tt);   // precise, not rsqrt approx
                    s = tt * c;
                }
                pA[t] = p; qA[t] = q; cA[t] = c; sA[t] = s;
            }
            __syncthreads();
            {   // sandwich phase: disjoint 2x2 blocks, thread t -> (i = t&63, 16 j's)
                int i = t & 63, jb = (t >> 6) << 4;
                int pi = pA[i], qi = qA[i];
                float ci = cA[i], si = sA[i];
#pragma unroll 4
                for (int jj = 0; jj < 16; jj++) {
                    int j = jb + jj;
                    int pj = pA[j], qj = qA[j];
                    float cj = cA[j], sj = sA[j];
                    float a = C[pi][pj], b = C[pi][qj], d = C[qi][pj], e = C[qi][qj];
                    float a1 = cj * a - sj * b, b1 = sj * a + cj * b;
                    float d1 = cj * d - sj * e, e1 = sj * d + cj * e;
                    C[pi][pj] = ci * a1 - si * d1;
                    C[qi][pj] = si * a1 + ci * d1;
                    C[pi][qj] = ci * b1 - si * e1;
                    C[qi][qj] = si * b1 + ci * e1;
                }
                // eigenvector accumulation V <- V*J (column rotations), disjoint cols
                int j2 = t & 63, kb = (t >> 6) << 5;
                int pj = pA[j2], qj = qA[j2];
                float cj = cA[j2], sj = sA[j2];
#pragma unroll 8
                for (int kk = 0; kk < 32; kk++) {
                    int k = kb + kk;
                    float x = Vm[k][pj], y = Vm[k][qj];
                    Vm[k][pj] = cj * x - sj * y;
                    Vm[k][qj] = sj * x + cj * y;
                }
            }
            __syncthreads();
        }
    }
    if (t < 128) diag[t] = C[t][t];
    __syncthreads();
    if (t < 128) {   // rank-select top-32 eigenvalues; order within top-32 irrelevant (projector)
        float dt = diag[t];
        int rank = 0;
        for (int j = 0; j < 128; j++) {
            float dj = diag[j];
            rank += (dj > dt) || (dj == dt && j < t);
        }
        if (rank < RP) {
            float* Bb = Bout + (size_t)bh * DIM * RP;
            for (int k = 0; k < 128; k++) Bb[k * RP + rank] = Vm[k][t];
        }
    }
}

// ---------------- projection: Y[row][r] = sum_k X[row][k] * B[k][r] ----------------
__global__ __launch_bounds__(256) void proj_kernel(const float* __restrict__ X,
                                                   const float* __restrict__ Bmat,
                                                   float* __restrict__ Y, int nrows) {
    int bh = blockIdx.y, rb = blockIdx.x;
    __shared__ float Bl[128][33];
    __shared__ float Xt[64][129];
    int t = threadIdx.x;
    for (int k = 0; k < 16; k++) {
        int idx = t + k * 256;
        Bl[idx >> 5][idx & 31] = Bmat[(size_t)bh * DIM * RP + idx];
    }
    const float* Xb = X + ((size_t)bh * nrows + (size_t)rb * 64) * DIM;
    for (int k = 0; k < 32; k++) {
        int idx = t + k * 256;
        Xt[idx >> 7][idx & 127] = Xb[idx];
    }
    __syncthreads();
    int row = t >> 2, rg = (t & 3) * 8;
    float acc[8] = {0.f, 0.f, 0.f, 0.f, 0.f, 0.f, 0.f, 0.f};
    for (int k = 0; k < 128; k++) {
        float xv = Xt[row][k];
#pragma unroll
        for (int rr = 0; rr < 8; rr++) acc[rr] += xv * Bl[k][rg + rr];
    }
    float* Yb = Y + ((size_t)bh * nrows + (size_t)rb * 64) * RP + row * RP + rg;
#pragma unroll
    for (int rr = 0; rr < 8; rr++) Yb[rr] = acc[rr];
}

// ---------------- fused flash-style attention: softmax(Qp Kp^T * scale) @ V ----------------
__global__ __launch_bounds__(256) void attn_kernel(const float* __restrict__ Qp,
                                                   const float* __restrict__ Kp,
                                                   const float* __restrict__ Vg,
                                                   float* __restrict__ Out) {
    const float SCALE = 0.1767766953f;  // 1/sqrt(32)
    int qt = blockIdx.x, bh = blockIdx.y;
    __shared__ float Kpl[128][36];      // 36: float4-aligned rows
    __shared__ float Vt[128][132];      // 132: float4-aligned rows
    __shared__ float Sl[64][129];       // scores/weights, conflict-free rows
    __shared__ float lL[64], aL[64];
    int t = threadIdx.x;
    int q = t >> 2, g = t & 3;          // 64 queries x 4 dim-groups of 32
    float qreg[32];
    const float* Qb = Qp + ((size_t)bh * QLEN + (size_t)qt * 64 + q) * RP;
#pragma unroll
    for (int r = 0; r < 32; r++) qreg[r] = Qb[r];
    float acc[32];
#pragma unroll
    for (int i = 0; i < 32; i++) acc[i] = 0.f;
    float m_run = -INFINITY, l_run = 0.0f;   // live only in threads t<64
    for (int kt = 0; kt < 32; kt++) {
        __syncthreads();
        const float4* Kpb = (const float4*)(Kp + ((size_t)bh * KLEN + (size_t)kt * 128) * RP);
        for (int k = 0; k < 4; k++) {
            int idx4 = t + k * 256;
            int j = idx4 >> 3, r4 = idx4 & 7;
            *(float4*)&Kpl[j][r4 * 4] = Kpb[idx4];
        }
        const float4* Vb = (const float4*)(Vg + ((size_t)bh * KLEN + (size_t)kt * 128) * DIM);
        for (int k = 0; k < 16; k++) {
            int idx4 = t + k * 256;
            int j = idx4 >> 5, c4 = idx4 & 31;
            *(float4*)&Vt[j][c4 * 4] = Vb[idx4];
        }
        __syncthreads();
        // scores: thread (q,g) computes 32 kv
        for (int jj = 0; jj < 32; jj++) {
            int j = g * 32 + jj;
            float s = 0.f;
#pragma unroll
            for (int r4 = 0; r4 < 8; r4++) {
                float4 kv = *(const float4*)&Kpl[j][r4 * 4];
                s += qreg[r4 * 4 + 0] * kv.x + qreg[r4 * 4 + 1] * kv.y
                   + qreg[r4 * 4 + 2] * kv.z + qreg[r4 * 4 + 3] * kv.w;
            }
            Sl[q][j] = s * SCALE;
        }
        __syncthreads();
        if (t < 64) {                     // online softmax bookkeeping, one thread per row
            float mx = m_run;
            for (int j = 0; j < 128; j++) mx = fmaxf(mx, Sl[t][j]);
            float alpha = __expf(m_run - mx);   // first tile: exp(-inf)=0
            float sum = 0.f;
            for (int j = 0; j < 128; j++) {
                float w = __expf(Sl[t][j] - mx);
                Sl[t][j] = w;
                sum += w;
            }
            l_run = l_run * alpha + sum;
            m_run = mx;
            aL[t] = alpha; lL[t] = l_run;
        }
        __syncthreads();
        float alpha = aL[q];
#pragma unroll
        for (int i = 0; i < 32; i++) acc[i] *= alpha;
        for (int j = 0; j < 128; j++) {
            float w = Sl[q][j];
#pragma unroll
            for (int i4 = 0; i4 < 8; i4++) {
                float4 vv = *(const float4*)&Vt[j][g * 32 + i4 * 4];
                acc[i4 * 4 + 0] += w * vv.x;
                acc[i4 * 4 + 1] += w * vv.y;
                acc[i4 * 4 + 2] += w * vv.z;
                acc[i4 * 4 + 3] += w * vv.w;
            }
        }
    }
    float linv = 1.0f / lL[q];
    float* Ob = Out + ((size_t)bh * QLEN + (size_t)qt * 64 + q) * DIM + g * 32;
#pragma unroll
    for (int i4 = 0; i4 < 8; i4++) {
        float4 o;
        o.x = acc[i4 * 4 + 0] * linv;
        o.y = acc[i4 * 4 + 1] * linv;
        o.z = acc[i4 * 4 + 2] * linv;
        o.w = acc[i4 * 4 + 3] * linv;
        *(float4*)&Ob[i4 * 4] = o;
    }
}

extern "C" void kernel_launch(void* const* d_in, const int* in_sizes, int n_in,
                              void* d_out, int out_size, void* d_ws, size_t ws_size,
                              hipStream_t stream) {
    const float* Q = (const float*)d_in[0];
    const float* K = (const float*)d_in[1];
    const float* V = (const float*)d_in[2];
    float* out = (float*)d_out;
    float* ws = (float*)d_ws;
    // workspace layout (floats): G 1048576 | S 8192 | B 262144 | Kp 8388608 | Qp 1048576  (~43 MB)
    float* G  = ws;
    float* S  = G + (size_t)BH * DIM * DIM;
    float* Bm = S + BH * DIM;
    float* Kp = Bm + (size_t)BH * DIM * RP;
    float* Qp = Kp + (size_t)BH * KLEN * RP;

    zero_kernel<<<1032, 256, 0, stream>>>((float4*)ws);                 // zero G + S exactly
    gram_kernel<<<dim3(4, BH), 256, 0, stream>>>(K, G, S);
    jacobi_kernel<<<BH, 256, 0, stream>>>(G, S, Bm);
    proj_kernel<<<dim3(KLEN / 64, BH), 256, 0, stream>>>(K, Bm, Kp, KLEN);
    proj_kernel<<<dim3(QLEN / 64, BH), 256, 0, stream>>>(Q, Bm, Qp, QLEN);
    attn_kernel<<<dim3(QLEN / 64, BH), 256, 0, stream>>>(Qp, Kp, V, out);
}

// Round 2
// 4065.741 us; speedup vs baseline: 1.5245x; 1.5245x over previous
//
#include <hip/hip_runtime.h>

#define BH 64
#define KLEN 4096
#define QLEN 512
#define DIM 128
#define RP 32
#define NSWEEP 6

// ---------------- Gram partials: Gpart[c] = Kc^T Kc over chunk c, Spart[c] = col sums ----------------
__global__ __launch_bounds__(256) void gram_kernel(const float* __restrict__ K,
                                                   float* __restrict__ Gpart,
                                                   float* __restrict__ Spart) {
    int bh = blockIdx.y, chunk = blockIdx.x;                  // 4 chunks of 1024 rows
    const float* Kb = K + ((size_t)bh * KLEN + (size_t)chunk * 1024) * DIM;
    __shared__ float Kt[32][129];                             // +1 pad: conflict-free column sums
    int t = threadIdx.x;
    int ty = t >> 4, tx = t & 15;                             // 16x16 threads, each 8x8 tile of C
    float acc[8][8];
#pragma unroll
    for (int i = 0; i < 8; i++)
#pragma unroll
        for (int j = 0; j < 8; j++) acc[i][j] = 0.f;
    float s_acc = 0.f;
    for (int tile = 0; tile < 32; tile++) {
        __syncthreads();
        for (int k = 0; k < 16; k++) {                        // load 32x128 coalesced
            int idx = t + k * 256;
            Kt[idx >> 7][idx & 127] = Kb[tile * 32 * DIM + idx];
        }
        __syncthreads();
#pragma unroll 4
        for (int r = 0; r < 32; r++) {
            float a_[8], b_[8];
#pragma unroll
            for (int i = 0; i < 8; i++) a_[i] = Kt[r][ty * 8 + i];
#pragma unroll
            for (int j = 0; j < 8; j++) b_[j] = Kt[r][tx * 8 + j];
#pragma unroll
            for (int i = 0; i < 8; i++)
#pragma unroll
                for (int j = 0; j < 8; j++) acc[i][j] += a_[i] * b_[j];
        }
        if (t < 128) { float ss = 0.f; for (int r = 0; r < 32; r++) ss += Kt[r][t]; s_acc += ss; }
    }
    // plain stores into this chunk's private slab — no atomics, no zero-init needed
    float* Gb = Gpart + ((size_t)chunk * BH + bh) * DIM * DIM;
#pragma unroll
    for (int i = 0; i < 8; i++)
#pragma unroll
        for (int j = 0; j < 8; j++) Gb[(ty * 8 + i) * DIM + tx * 8 + j] = acc[i][j];
    if (t < 128) Spart[((size_t)chunk * BH + bh) * DIM + t] = s_acc;
}

// ---------------- Jacobi eigensolver on C = sum_c Gpart - S S^T / n, top-32 basis -> Bout ----------------
__global__ __launch_bounds__(1024) void jacobi_kernel(const float* __restrict__ Gpart,
                                                      const float* __restrict__ Spart,
                                                      float* __restrict__ Bout) {
    __shared__ float C[128][129];   // +1 pad
    __shared__ float Vm[128][129];
    __shared__ int   pA[2][64], qA[2][64];
    __shared__ float cA[2][64], sA[2][64];
    __shared__ float diag[128];     // also used as summed-S at load time
    int bh = blockIdx.x, t = threadIdx.x;
    const size_t gslab = (size_t)BH * DIM * DIM;
    const float* Gb = Gpart + (size_t)bh * DIM * DIM;

    if (t < 128) {
        float s = 0.f;
#pragma unroll
        for (int c = 0; c < 4; c++) s += Spart[((size_t)c * BH + bh) * DIM + t];
        diag[t] = s;
    }
    __syncthreads();
    for (int k = 0; k < 16; k++) {
        int idx = t + k * 1024;
        int i = idx >> 7, j = idx & 127;
        float g = Gb[idx] + Gb[gslab + idx] + Gb[2 * gslab + idx] + Gb[3 * gslab + idx];
        C[i][j] = g - diag[i] * diag[j] * (1.0f / 4096.0f);
        Vm[i][j] = (i == j) ? 1.0f : 0.0f;
    }
    __syncthreads();
    // prologue: angles for round 0 into buffer 0
    if (t < 64) {
        int p, q;
        if (t == 0) { p = 127; q = 0; }
        else { p = t % 127; q = (127 - t) % 127; }
        float app = C[p][p], aqq = C[q][q], apq = C[p][q];
        float c = 1.0f, s = 0.0f;
        if (apq != 0.0f) {
            float tau = (aqq - app) / (2.0f * apq);
            float root = sqrtf(1.0f + tau * tau);
            float tt = (tau >= 0.0f) ? 1.0f / (tau + root) : 1.0f / (tau - root);
            c = 1.0f / sqrtf(1.0f + tt * tt);
            s = tt * c;
        }
        pA[0][t] = p; qA[0][t] = q; cA[0][t] = c; sA[0][t] = s;
    }
    __syncthreads();

    const int NR = NSWEEP * 127;
    for (int sr = 0; sr < NR; sr++) {
        int cur = sr & 1, nxt = cur ^ 1;
        // ---- phase A: sandwich C with angles[cur]; 4096 disjoint 2x2 block tasks ----
        {
            int i = t & 63, jb = (t >> 6) << 2;      // jb wave-uniform
            int pi = pA[cur][i], qi = qA[cur][i];
            float ci = cA[cur][i], si = sA[cur][i];
#pragma unroll
            for (int jj = 0; jj < 4; jj++) {
                int j = jb + jj;
                int pj = pA[cur][j], qj = qA[cur][j];
                float cj = cA[cur][j], sj = sA[cur][j];
                float a = C[pi][pj], b = C[pi][qj], d = C[qi][pj], e = C[qi][qj];
                float a1 = cj * a - sj * b, b1 = sj * a + cj * b;
                float d1 = cj * d - sj * e, e1 = sj * d + cj * e;
                C[pi][pj] = ci * a1 - si * d1;
                C[qi][pj] = si * a1 + ci * d1;
                C[pi][qj] = ci * b1 - si * e1;
                C[qi][qj] = si * b1 + ci * e1;
            }
        }
        __syncthreads();
        // ---- phase B: Vm column rotations (waves 1..15) || next-round angles (wave 0) ----
        if (t < 64) {
            if (sr + 1 < NR) {
                int r = (sr + 1) % 127;
                int p, q;
                if (t == 0) { p = 127; q = r; }
                else { p = (r + t) % 127; q = (r + 127 - t) % 127; }
                float app = C[p][p], aqq = C[q][q], apq = C[p][q];
                float c = 1.0f, s = 0.0f;
                if (apq != 0.0f) {
                    float tau = (aqq - app) / (2.0f * apq);
                    float root = sqrtf(1.0f + tau * tau);
                    float tt = (tau >= 0.0f) ? 1.0f / (tau + root) : 1.0f / (tau - root);
                    c = 1.0f / sqrtf(1.0f + tt * tt);
                    s = tt * c;
                }
                pA[nxt][t] = p; qA[nxt][t] = q; cA[nxt][t] = c; sA[nxt][t] = s;
            }
        } else {
            int tt = t - 64;
            for (int tau = tt; tau < 8192; tau += 960) {
                int j2 = tau & 63, k = tau >> 6;
                int pj = pA[cur][j2], qj = qA[cur][j2];
                float cj = cA[cur][j2], sj = sA[cur][j2];
                float x = Vm[k][pj], y = Vm[k][qj];
                Vm[k][pj] = cj * x - sj * y;
                Vm[k][qj] = sj * x + cj * y;
            }
        }
        __syncthreads();
    }

    if (t < 128) diag[t] = C[t][t];
    __syncthreads();
    if (t < 128) {   // rank-select top-32 eigenvalues; order within top-32 irrelevant (projector)
        float dt = diag[t];
        int rank = 0;
        for (int j = 0; j < 128; j++) {
            float dj = diag[j];
            rank += (dj > dt) || (dj == dt && j < t);
        }
        if (rank < RP) {
            float* Bb = Bout + (size_t)bh * DIM * RP;
            for (int k = 0; k < 128; k++) Bb[k * RP + rank] = Vm[k][t];
        }
    }
}

// ---------------- projection: Y[row][r] = sum_k X[row][k] * B[k][r] ----------------
__global__ __launch_bounds__(256) void proj_kernel(const float* __restrict__ X,
                                                   const float* __restrict__ Bmat,
                                                   float* __restrict__ Y, int nrows) {
    int bh = blockIdx.y, rb = blockIdx.x;
    __shared__ float Bl[128][33];
    __shared__ float Xt[64][129];
    int t = threadIdx.x;
    for (int k = 0; k < 16; k++) {
        int idx = t + k * 256;
        Bl[idx >> 5][idx & 31] = Bmat[(size_t)bh * DIM * RP + idx];
    }
    const float* Xb = X + ((size_t)bh * nrows + (size_t)rb * 64) * DIM;
    for (int k = 0; k < 32; k++) {
        int idx = t + k * 256;
        Xt[idx >> 7][idx & 127] = Xb[idx];
    }
    __syncthreads();
    int row = t >> 2, rg = (t & 3) * 8;
    float acc[8] = {0.f, 0.f, 0.f, 0.f, 0.f, 0.f, 0.f, 0.f};
    for (int k = 0; k < 128; k++) {
        float xv = Xt[row][k];
#pragma unroll
        for (int rr = 0; rr < 8; rr++) acc[rr] += xv * Bl[k][rg + rr];
    }
    float* Yb = Y + ((size_t)bh * nrows + (size_t)rb * 64) * RP + row * RP + rg;
#pragma unroll
    for (int rr = 0; rr < 8; rr++) Yb[rr] = acc[rr];
}

// ---------------- fused flash-style attention: softmax(Qp Kp^T * scale) @ V ----------------
__global__ __launch_bounds__(256) void attn_kernel(const float* __restrict__ Qp,
                                                   const float* __restrict__ Kp,
                                                   const float* __restrict__ Vg,
                                                   float* __restrict__ Out) {
    const float SCALE = 0.1767766953f;  // 1/sqrt(32)
    int qt = blockIdx.x, bh = blockIdx.y;
    __shared__ float Kpl[128][36];      // 36: float4-aligned rows
    __shared__ float Vt[128][132];      // 132: float4-aligned rows
    __shared__ float Sl[64][129];       // scores/weights, conflict-free rows
    __shared__ float lL[64], aL[64];
    int t = threadIdx.x;
    int q = t >> 2, g = t & 3;          // 64 queries x 4 dim-groups of 32
    float qreg[32];
    const float* Qb = Qp + ((size_t)bh * QLEN + (size_t)qt * 64 + q) * RP;
#pragma unroll
    for (int r = 0; r < 32; r++) qreg[r] = Qb[r];
    float acc[32];
#pragma unroll
    for (int i = 0; i < 32; i++) acc[i] = 0.f;
    float m_run = -INFINITY, l_run = 0.0f;   // live only in threads t<64
    for (int kt = 0; kt < 32; kt++) {
        __syncthreads();
        const float4* Kpb = (const float4*)(Kp + ((size_t)bh * KLEN + (size_t)kt * 128) * RP);
        for (int k = 0; k < 4; k++) {
            int idx4 = t + k * 256;
            int j = idx4 >> 3, r4 = idx4 & 7;
            *(float4*)&Kpl[j][r4 * 4] = Kpb[idx4];
        }
        const float4* Vb = (const float4*)(Vg + ((size_t)bh * KLEN + (size_t)kt * 128) * DIM);
        for (int k = 0; k < 16; k++) {
            int idx4 = t + k * 256;
            int j = idx4 >> 5, c4 = idx4 & 31;
            *(float4*)&Vt[j][c4 * 4] = Vb[idx4];
        }
        __syncthreads();
        // scores: thread (q,g) computes 32 kv
        for (int jj = 0; jj < 32; jj++) {
            int j = g * 32 + jj;
            float s = 0.f;
#pragma unroll
            for (int r4 = 0; r4 < 8; r4++) {
                float4 kv = *(const float4*)&Kpl[j][r4 * 4];
                s += qreg[r4 * 4 + 0] * kv.x + qreg[r4 * 4 + 1] * kv.y
                   + qreg[r4 * 4 + 2] * kv.z + qreg[r4 * 4 + 3] * kv.w;
            }
            Sl[q][j] = s * SCALE;
        }
        __syncthreads();
        if (t < 64) {                     // online softmax bookkeeping, one thread per row
            float mx = m_run;
            for (int j = 0; j < 128; j++) mx = fmaxf(mx, Sl[t][j]);
            float alpha = __expf(m_run - mx);   // first tile: exp(-inf)=0
            float sum = 0.f;
            for (int j = 0; j < 128; j++) {
                float w = __expf(Sl[t][j] - mx);
                Sl[t][j] = w;
                sum += w;
            }
            l_run = l_run * alpha + sum;
            m_run = mx;
            aL[t] = alpha; lL[t] = l_run;
        }
        __syncthreads();
        float alpha = aL[q];
#pragma unroll
        for (int i = 0; i < 32; i++) acc[i] *= alpha;
        for (int j = 0; j < 128; j++) {
            float w = Sl[q][j];
#pragma unroll
            for (int i4 = 0; i4 < 8; i4++) {
                float4 vv = *(const float4*)&Vt[j][g * 32 + i4 * 4];
                acc[i4 * 4 + 0] += w * vv.x;
                acc[i4 * 4 + 1] += w * vv.y;
                acc[i4 * 4 + 2] += w * vv.z;
                acc[i4 * 4 + 3] += w * vv.w;
            }
        }
    }
    float linv = 1.0f / lL[q];
    float* Ob = Out + ((size_t)bh * QLEN + (size_t)qt * 64 + q) * DIM + g * 32;
#pragma unroll
    for (int i4 = 0; i4 < 8; i4++) {
        float4 o;
        o.x = acc[i4 * 4 + 0] * linv;
        o.y = acc[i4 * 4 + 1] * linv;
        o.z = acc[i4 * 4 + 2] * linv;
        o.w = acc[i4 * 4 + 3] * linv;
        *(float4*)&Ob[i4 * 4] = o;
    }
}

extern "C" void kernel_launch(void* const* d_in, const int* in_sizes, int n_in,
                              void* d_out, int out_size, void* d_ws, size_t ws_size,
                              hipStream_t stream) {
    const float* Q = (const float*)d_in[0];
    const float* K = (const float*)d_in[1];
    const float* V = (const float*)d_in[2];
    float* out = (float*)d_out;
    float* ws = (float*)d_ws;
    // workspace layout (floats):
    //   G 1048576 | S 8192 | B 262144 | Kp 8388608 | Qp 1048576   (same 43 MB footprint as before)
    // Gram partials (4 slabs G + 4 slabs S = 4227072 floats) live INSIDE the Kp region,
    // which is only written later by proj_kernel — no extra workspace needed, no atomics, no zeroing.
    float* G  = ws;                                   // unused this round (kept for layout stability)
    float* S  = G + (size_t)BH * DIM * DIM;
    float* Bm = S + BH * DIM;
    float* Kp = Bm + (size_t)BH * DIM * RP;
    float* Qp = Kp + (size_t)BH * KLEN * RP;
    float* Gpart = Kp;                                // 4 * BH * 128 * 128 floats
    float* Spart = Gpart + (size_t)4 * BH * DIM * DIM; // 4 * BH * 128 floats

    gram_kernel<<<dim3(4, BH), 256, 0, stream>>>(K, Gpart, Spart);
    jacobi_kernel<<<BH, 1024, 0, stream>>>(Gpart, Spart, Bm);
    proj_kernel<<<dim3(KLEN / 64, BH), 256, 0, stream>>>(K, Bm, Kp, KLEN);
    proj_kernel<<<dim3(QLEN / 64, BH), 256, 0, stream>>>(Q, Bm, Qp, QLEN);
    attn_kernel<<<dim3(QLEN / 64, BH), 256, 0, stream>>>(Qp, Kp, V, out);
}